// Round 1
// baseline (59.134 us; speedup 1.0000x reference)
//
#include <hip/hip_runtime.h>

#define MARGIN 0.5f
#define NON_MATCH_W 1.0f

// ws layout: ws[0] = raw match sum, ws[1] = raw nonmatch hinge sum
__global__ void cl_zero_ws(float* ws) {
    ws[0] = 0.0f;
    ws[1] = 0.0f;
}

__global__ __launch_bounds__(256) void cl_main(
    const float* __restrict__ outA, const float* __restrict__ outB,
    const int* __restrict__ matchA, const int* __restrict__ matchB,
    const int* __restrict__ nonMatchA, const int* __restrict__ nonMatchB,
    float* __restrict__ ws, int N, int M, int Mn, int B)
{
    const int totalMatch = B * M;
    const int total = totalMatch + B * Mn;
    const int idx = blockIdx.x * blockDim.x + threadIdx.x;

    float msum = 0.0f;
    float nsum = 0.0f;

    if (idx < totalMatch) {
        // match pair: flat index == b*M + m
        const int b = idx / M;
        const int ia = matchA[idx];
        const int ib = matchB[idx];
        const float4* ra = reinterpret_cast<const float4*>(outA + ((size_t)b * N + ia) * 16);
        const float4* rb = reinterpret_cast<const float4*>(outB + ((size_t)b * N + ib) * 16);
#pragma unroll
        for (int k = 0; k < 4; ++k) {
            const float4 a = ra[k];
            const float4 bb = rb[k];
            const float dx = a.x - bb.x;
            const float dy = a.y - bb.y;
            const float dz = a.z - bb.z;
            const float dw = a.w - bb.w;
            msum += dx * dx + dy * dy + dz * dz + dw * dw;
        }
    } else if (idx < total) {
        const int j = idx - totalMatch;   // flat index b*Mn + m
        const int b = j / Mn;
        const int ia = nonMatchA[j];
        const int ib = nonMatchB[j];
        const float4* ra = reinterpret_cast<const float4*>(outA + ((size_t)b * N + ia) * 16);
        const float4* rb = reinterpret_cast<const float4*>(outB + ((size_t)b * N + ib) * 16);
#pragma unroll
        for (int k = 0; k < 4; ++k) {
            const float4 a = ra[k];
            const float4 bb = rb[k];
            const float dx = a.x - bb.x;
            const float dy = a.y - bb.y;
            const float dz = a.z - bb.z;
            const float dw = a.w - bb.w;
            nsum += fmaxf(0.0f, MARGIN - dx * dx);
            nsum += fmaxf(0.0f, MARGIN - dy * dy);
            nsum += fmaxf(0.0f, MARGIN - dz * dz);
            nsum += fmaxf(0.0f, MARGIN - dw * dw);
        }
    }

    // wave-64 butterfly-free down reduction of both partial sums
#pragma unroll
    for (int off = 32; off > 0; off >>= 1) {
        msum += __shfl_down(msum, off, 64);
        nsum += __shfl_down(nsum, off, 64);
    }

    if ((threadIdx.x & 63) == 0) {
        if (msum != 0.0f) atomicAdd(&ws[0], msum);
        if (nsum != 0.0f) atomicAdd(&ws[1], nsum);
    }
}

__global__ void cl_finalize(const float* __restrict__ ws, float* __restrict__ out,
                            float invM, float invMn) {
    const float m = ws[0] * invM;
    const float n = ws[1] * NON_MATCH_W * invMn;
    out[0] = m + n;   // contrastiveLossSum
    out[1] = m;       // matchLossSum
    out[2] = n;       // nonMatchLossSum
}

extern "C" void kernel_launch(void* const* d_in, const int* in_sizes, int n_in,
                              void* d_out, int out_size, void* d_ws, size_t ws_size,
                              hipStream_t stream) {
    const float* outA = (const float*)d_in[0];
    const float* outB = (const float*)d_in[1];
    const int* matchA = (const int*)d_in[2];
    const int* matchB = (const int*)d_in[3];
    const int* nonMatchA = (const int*)d_in[4];
    const int* nonMatchB = (const int*)d_in[5];
    float* out = (float*)d_out;
    float* ws = (float*)d_ws;

    const int B = 4;
    const int D = 16;
    const int N = in_sizes[0] / (B * D);   // 307200
    const int M = in_sizes[2] / B;         // 5000
    const int Mn = in_sizes[4] / B;        // 50000

    const int total = B * M + B * Mn;      // 220000
    const int block = 256;
    const int grid = (total + block - 1) / block;

    cl_zero_ws<<<1, 1, 0, stream>>>(ws);
    cl_main<<<grid, block, 0, stream>>>(outA, outB, matchA, matchB,
                                        nonMatchA, nonMatchB, ws, N, M, Mn, B);
    cl_finalize<<<1, 1, 0, stream>>>(ws, out, 1.0f / (float)M, 1.0f / (float)Mn);
}

// Round 2
// 20.282 us; speedup vs baseline: 2.9156x; 2.9156x over previous
//
#include <hip/hip_runtime.h>

#define MARGIN 0.5f
#define NON_MATCH_W 1.0f

// One thread per (pair, k) where k indexes the 4 float4 chunks of a 16-float row.
// Lanes 4p..4p+3 of a wave read contiguous 64B of the same row -> coalesced
// 64B segments, 16 scattered segments per wave-load instead of 64.
__global__ __launch_bounds__(256) void cl_main(
    const float* __restrict__ outA, const float* __restrict__ outB,
    const int* __restrict__ matchA, const int* __restrict__ matchB,
    const int* __restrict__ nonMatchA, const int* __restrict__ nonMatchB,
    float* __restrict__ partials, int N, int M, int Mn, int B)
{
    const int totalMatch4 = B * M * 4;
    const int total4 = (B * M + B * Mn) * 4;
    const int gid = blockIdx.x * blockDim.x + threadIdx.x;

    float msum = 0.0f;
    float nsum = 0.0f;

    if (gid < total4) {
        const int k = gid & 3;          // which float4 of the row
        const int pairg = gid >> 2;     // global pair id across match+nonmatch

        if (gid < totalMatch4) {
            const int pair = pairg;             // b*M + m
            const int b = pair / M;
            const int ia = matchA[pair];
            const int ib = matchB[pair];
            const float4 a = reinterpret_cast<const float4*>(
                outA + ((size_t)b * N + ia) * 16)[k];
            const float4 bb = reinterpret_cast<const float4*>(
                outB + ((size_t)b * N + ib) * 16)[k];
            const float dx = a.x - bb.x;
            const float dy = a.y - bb.y;
            const float dz = a.z - bb.z;
            const float dw = a.w - bb.w;
            msum = dx * dx + dy * dy + dz * dz + dw * dw;
        } else {
            const int pair = pairg - B * M;     // b*Mn + m
            const int b = pair / Mn;
            const int ia = nonMatchA[pair];
            const int ib = nonMatchB[pair];
            const float4 a = reinterpret_cast<const float4*>(
                outA + ((size_t)b * N + ia) * 16)[k];
            const float4 bb = reinterpret_cast<const float4*>(
                outB + ((size_t)b * N + ib) * 16)[k];
            const float dx = a.x - bb.x;
            const float dy = a.y - bb.y;
            const float dz = a.z - bb.z;
            const float dw = a.w - bb.w;
            nsum = fmaxf(0.0f, MARGIN - dx * dx)
                 + fmaxf(0.0f, MARGIN - dy * dy)
                 + fmaxf(0.0f, MARGIN - dz * dz)
                 + fmaxf(0.0f, MARGIN - dw * dw);
        }
    }

    // wave-64 reduction of both partial sums
#pragma unroll
    for (int off = 32; off > 0; off >>= 1) {
        msum += __shfl_down(msum, off, 64);
        nsum += __shfl_down(nsum, off, 64);
    }

    // block reduction via LDS (4 waves/block), then one partial pair per block
    __shared__ float sm[4];
    __shared__ float sn[4];
    const int wave = threadIdx.x >> 6;
    if ((threadIdx.x & 63) == 0) {
        sm[wave] = msum;
        sn[wave] = nsum;
    }
    __syncthreads();
    if (threadIdx.x == 0) {
        partials[2 * blockIdx.x]     = sm[0] + sm[1] + sm[2] + sm[3];
        partials[2 * blockIdx.x + 1] = sn[0] + sn[1] + sn[2] + sn[3];
    }
}

// Single-block deterministic reduction of per-block partials -> 3 outputs.
__global__ __launch_bounds__(256) void cl_finalize(
    const float* __restrict__ partials, float* __restrict__ out,
    int nblocks, float invM, float invMn)
{
    float msum = 0.0f;
    float nsum = 0.0f;
    for (int i = threadIdx.x; i < nblocks; i += 256) {
        msum += partials[2 * i];
        nsum += partials[2 * i + 1];
    }
#pragma unroll
    for (int off = 32; off > 0; off >>= 1) {
        msum += __shfl_down(msum, off, 64);
        nsum += __shfl_down(nsum, off, 64);
    }
    __shared__ float sm[4];
    __shared__ float sn[4];
    const int wave = threadIdx.x >> 6;
    if ((threadIdx.x & 63) == 0) {
        sm[wave] = msum;
        sn[wave] = nsum;
    }
    __syncthreads();
    if (threadIdx.x == 0) {
        const float m = (sm[0] + sm[1] + sm[2] + sm[3]) * invM;
        const float n = (sn[0] + sn[1] + sn[2] + sn[3]) * NON_MATCH_W * invMn;
        out[0] = m + n;
        out[1] = m;
        out[2] = n;
    }
}

extern "C" void kernel_launch(void* const* d_in, const int* in_sizes, int n_in,
                              void* d_out, int out_size, void* d_ws, size_t ws_size,
                              hipStream_t stream) {
    const float* outA = (const float*)d_in[0];
    const float* outB = (const float*)d_in[1];
    const int* matchA = (const int*)d_in[2];
    const int* matchB = (const int*)d_in[3];
    const int* nonMatchA = (const int*)d_in[4];
    const int* nonMatchB = (const int*)d_in[5];
    float* out = (float*)d_out;
    float* partials = (float*)d_ws;

    const int B = 4;
    const int D = 16;
    const int N = in_sizes[0] / (B * D);   // 307200
    const int M = in_sizes[2] / B;         // 5000
    const int Mn = in_sizes[4] / B;        // 50000

    const int total4 = (B * M + B * Mn) * 4;   // 880000
    const int block = 256;
    const int grid = (total4 + block - 1) / block;   // 3438

    cl_main<<<grid, block, 0, stream>>>(outA, outB, matchA, matchB,
                                        nonMatchA, nonMatchB, partials, N, M, Mn, B);
    cl_finalize<<<1, block, 0, stream>>>(partials, out, grid,
                                         1.0f / (float)M, 1.0f / (float)Mn);
}

// Round 3
// 18.832 us; speedup vs baseline: 3.1401x; 1.0770x over previous
//
#include <hip/hip_runtime.h>

#define MARGIN 0.5f
#define NON_MATCH_W 1.0f

__device__ __forceinline__ float4 ld_row_chunk(const float* __restrict__ base,
                                               int b, int row, int k, int N) {
    return reinterpret_cast<const float4*>(base + ((size_t)b * N + row) * 16)[k];
}

__device__ __forceinline__ float sqdiff(float4 a, float4 b) {
    const float dx = a.x - b.x, dy = a.y - b.y, dz = a.z - b.z, dw = a.w - b.w;
    return dx * dx + dy * dy + dz * dz + dw * dw;
}

__device__ __forceinline__ float hinge(float4 a, float4 b) {
    const float dx = a.x - b.x, dy = a.y - b.y, dz = a.z - b.z, dw = a.w - b.w;
    return fmaxf(0.0f, MARGIN - dx * dx) + fmaxf(0.0f, MARGIN - dy * dy)
         + fmaxf(0.0f, MARGIN - dz * dz) + fmaxf(0.0f, MARGIN - dw * dw);
}

// 2 items per thread, item = (pair, k) with 4 float4-chunks per pair.
// item2 = item1 + half: always in the nonmatch region; both region
// boundaries (80000, 440000) are multiples of 64 -> wave-uniform branches.
__global__ __launch_bounds__(256) void cl_main(
    const float* __restrict__ outA, const float* __restrict__ outB,
    const int* __restrict__ matchA, const int* __restrict__ matchB,
    const int* __restrict__ nonMatchA, const int* __restrict__ nonMatchB,
    float* __restrict__ partials, int N, int M, int Mn, int B)
{
    const int totalMatch4 = B * M * 4;            // 80000
    const int half = (B * M + B * Mn) * 2;        // 440000 (= total4/2)
    const int gid = blockIdx.x * blockDim.x + threadIdx.x;

    float msum = 0.0f;
    float nsum = 0.0f;

    if (gid < half) {
        // ---- item 2 (always nonmatch): issue its loads first for MLP
        const int it2 = gid + half;
        const int k2 = it2 & 3;
        const int pair2 = (it2 >> 2) - B * M;
        const int b2 = pair2 / Mn;
        const float4 a2 = ld_row_chunk(outA, b2, nonMatchA[pair2], k2, N);
        const float4 c2 = ld_row_chunk(outB, b2, nonMatchB[pair2], k2, N);

        // ---- item 1
        const int k1 = gid & 3;
        const int p1 = gid >> 2;
        if (gid < totalMatch4) {
            const int b1 = p1 / M;
            const float4 a1 = ld_row_chunk(outA, b1, matchA[p1], k1, N);
            const float4 c1 = ld_row_chunk(outB, b1, matchB[p1], k1, N);
            msum = sqdiff(a1, c1);
        } else {
            const int pair1 = p1 - B * M;
            const int b1 = pair1 / Mn;
            const float4 a1 = ld_row_chunk(outA, b1, nonMatchA[pair1], k1, N);
            const float4 c1 = ld_row_chunk(outB, b1, nonMatchB[pair1], k1, N);
            nsum = hinge(a1, c1);
        }
        nsum += hinge(a2, c2);
    }

    // wave-64 reduction of both partials
#pragma unroll
    for (int off = 32; off > 0; off >>= 1) {
        msum += __shfl_down(msum, off, 64);
        nsum += __shfl_down(nsum, off, 64);
    }

    __shared__ float sm[4];
    __shared__ float sn[4];
    const int wave = threadIdx.x >> 6;
    if ((threadIdx.x & 63) == 0) {
        sm[wave] = msum;
        sn[wave] = nsum;
    }
    __syncthreads();
    if (threadIdx.x == 0) {
        partials[2 * blockIdx.x]     = sm[0] + sm[1] + sm[2] + sm[3];
        partials[2 * blockIdx.x + 1] = sn[0] + sn[1] + sn[2] + sn[3];
    }
}

// Single-block deterministic reduction of per-block partials -> 3 outputs.
__global__ __launch_bounds__(256) void cl_finalize(
    const float* __restrict__ partials, float* __restrict__ out,
    int nblocks, float invM, float invMn)
{
    float msum = 0.0f;
    float nsum = 0.0f;
    const float2* p2 = reinterpret_cast<const float2*>(partials);
    for (int i = threadIdx.x; i < nblocks; i += 256) {
        const float2 v = p2[i];
        msum += v.x;
        nsum += v.y;
    }
#pragma unroll
    for (int off = 32; off > 0; off >>= 1) {
        msum += __shfl_down(msum, off, 64);
        nsum += __shfl_down(nsum, off, 64);
    }
    __shared__ float sm[4];
    __shared__ float sn[4];
    const int wave = threadIdx.x >> 6;
    if ((threadIdx.x & 63) == 0) {
        sm[wave] = msum;
        sn[wave] = nsum;
    }
    __syncthreads();
    if (threadIdx.x == 0) {
        const float m = (sm[0] + sm[1] + sm[2] + sm[3]) * invM;
        const float n = (sn[0] + sn[1] + sn[2] + sn[3]) * NON_MATCH_W * invMn;
        out[0] = m + n;
        out[1] = m;
        out[2] = n;
    }
}

extern "C" void kernel_launch(void* const* d_in, const int* in_sizes, int n_in,
                              void* d_out, int out_size, void* d_ws, size_t ws_size,
                              hipStream_t stream) {
    const float* outA = (const float*)d_in[0];
    const float* outB = (const float*)d_in[1];
    const int* matchA = (const int*)d_in[2];
    const int* matchB = (const int*)d_in[3];
    const int* nonMatchA = (const int*)d_in[4];
    const int* nonMatchB = (const int*)d_in[5];
    float* out = (float*)d_out;
    float* partials = (float*)d_ws;

    const int B = 4;
    const int D = 16;
    const int N = in_sizes[0] / (B * D);   // 307200
    const int M = in_sizes[2] / B;         // 5000
    const int Mn = in_sizes[4] / B;        // 50000

    const int half = (B * M + B * Mn) * 2; // 440000 threads, 2 items each
    const int block = 256;
    const int grid = (half + block - 1) / block;   // 1719

    cl_main<<<grid, block, 0, stream>>>(outA, outB, matchA, matchB,
                                        nonMatchA, nonMatchB, partials, N, M, Mn, B);
    cl_finalize<<<1, block, 0, stream>>>(partials, out, grid,
                                         1.0f / (float)M, 1.0f / (float)Mn);
}